// Round 5
// baseline (240.506 us; speedup 1.0000x reference)
//
#include <hip/hip_runtime.h>
#include <hip/hip_bf16.h>

#define NN 100000
#define DEG 32
#define IN_DIM 25
#define AGG_DIM 75
#define OUT_DIM 128
#define BLK 256

#define GNPB 32                  // nodes per gather chunk
#define GEPC (GNPB * DEG)        // 1024 edges
#define GGRID (NN / GNPB)        // 3125 blocks, 1 chunk each

#define MNPB 16                  // nodes per mm chunk (MFMA M-tile)
#define MGRID 3125               // 2 chunks per block -> 6250
#define KPAD 104                 // A-tile row stride (ushorts)

#define PREP_NPB 128
#define PREP_GRID ((NN + PREP_NPB - 1) / PREP_NPB)   // 782

typedef __attribute__((ext_vector_type(8))) short short8;
typedef __attribute__((ext_vector_type(4))) float f32x4;

static __device__ __forceinline__ unsigned f2bf(float x) {
    __hip_bfloat16 h = __float2bfloat16(x);
    return (unsigned)*reinterpret_cast<unsigned short*>(&h);
}
static __device__ __forceinline__ float bflo(unsigned v) { return __uint_as_float(v << 16); }
static __device__ __forceinline__ float bfhi(unsigned v) { return __uint_as_float(v & 0xffff0000u); }
static __device__ __forceinline__ void gload16(const void* g, void* l) {
    __builtin_amdgcn_global_load_lds(
        (const __attribute__((address_space(1))) unsigned*)g,
        (__attribute__((address_space(3))) unsigned*)l, 16, 0, 0);
}

// ws: [0,1024) bnbuf; [1024, +3.2MB) tabA [NN][16]u16 (feat 0-15);
//     then tabB [NN][16]u16 (feat 16-24 + pad). Total 6.4 MB + 1 KB (proven size).
// d_out chunk c (16 nodes): dwords [c*2048, +2048) = z rows; gather passes park
// aggA (384 dw) + aggB (256 dw) in the first 640 dwords; mm stages them to LDS
// (barrier) before overwriting with z. Same-block read->write, no cross-block race.

__global__ __launch_bounds__(BLK) void prep(const float* __restrict__ h,
                                            ushort* __restrict__ tabA,
                                            ushort* __restrict__ tabB,
                                            float* __restrict__ bnbuf) {
    __shared__ float hls[PREP_NPB * IN_DIM];     // 12.8 KB
    const int t = threadIdx.x, bk = blockIdx.x;
    if (bk == 0 && t < 2 * OUT_DIM) bnbuf[t] = 0.0f;
    const int base4 = bk * (PREP_NPB * IN_DIM / 4);      // *800
    const float4* h4 = (const float4*)h;
    for (int i = t; i < PREP_NPB * IN_DIM / 4; i += BLK)
        if (base4 + i < NN * IN_DIM / 4) ((float4*)hls)[i] = h4[base4 + i];
    __syncthreads();
    const int nl = t >> 1, sel = t & 1;
    const int node = bk * PREP_NPB + nl;
    if (node < NN) {
        const float* row = hls + nl * IN_DIM;
        unsigned u[8];
        if (sel == 0) {
            #pragma unroll
            for (int k = 0; k < 8; ++k) u[k] = f2bf(row[2*k]) | (f2bf(row[2*k+1]) << 16);
            uint4* d = (uint4*)(tabA + (size_t)node * 16);
            d[0] = make_uint4(u[0],u[1],u[2],u[3]);
            d[1] = make_uint4(u[4],u[5],u[6],u[7]);
        } else {
            #pragma unroll
            for (int k = 0; k < 4; ++k) u[k] = f2bf(row[16+2*k]) | (f2bf(row[17+2*k]) << 16);
            u[4] = f2bf(row[24]); u[5] = 0u; u[6] = 0u; u[7] = 0u;
            uint4* d = (uint4*)(tabB + (size_t)node * 16);
            d[0] = make_uint4(u[0],u[1],u[2],u[3]);
            d[1] = make_uint4(u[4],u[5],u[6],u[7]);
        }
    }
}

// NF: features in this pass; ODW: agg dwords/node; OOFF: dword offset in chunk slab
template<int NF, int ODW, int OOFF>
__global__ __launch_bounds__(BLK) void gather_pass(
    const ushort* __restrict__ tab, const int* __restrict__ esrc,
    unsigned* __restrict__ zdw)
{
    __shared__ __align__(1024) unsigned E_s[GEPC * 8];   // 32 KB: [1024 rows][8 dw]
    __shared__ int ids_s[GEPC];                          // 4 KB
    __shared__ unsigned aggT[GNPB * ODW];                // 3 / 2 KB

    const int t = threadIdx.x;
    const int lane = t & 63, wv = t >> 6;
    const int g0 = blockIdx.x;

    ((int4*)ids_s)[t] = ((const int4*)(esrc + g0 * GEPC))[t];
    __syncthreads();

    // 32-B row gather: 2 lanes/row, 32 rows/instr, 32 instrs/chunk (8 per wave)
    const int lsub = lane >> 1, prt = lane & 1;
    #pragma unroll
    for (int i = 0; i < 8; ++i) {
        const int g = wv * 8 + i;
        const int src = ids_s[g * 32 + lsub];
        gload16((const char*)tab + ((size_t)(unsigned)src << 5) + (prt << 4),
                (char*)E_s + (g << 10));
    }
    __syncthreads();   // drains vmcnt

    // reduce: 8 threads/node, dword f covers features 2f, 2f+1
    const int nl = t >> 3, f = t & 7;
    constexpr int SEC = (NF + 1) / 2;                    // 8 (A) or 5 (B)
    if (f < SEC) {
        const bool hasHi = (2 * f + 1 < NF);
        float s0=0.f,q0=0.f,m0=-3.4e38f, s1=0.f,q1=0.f,m1=-3.4e38f;
        const unsigned base = nl * 256 + f;
        #pragma unroll
        for (int e = 0; e < 32; ++e) {
            const int ee = (e + nl) & 31;                // rotation: 2-way banks, commutative
            const unsigned v = E_s[base + ee * 8];
            const float lo = bflo(v), hi = bfhi(v);
            s0 += lo; q0 = fmaf(lo,lo,q0); m0 = fmaxf(m0, lo);
            s1 += hi; q1 = fmaf(hi,hi,q1); m1 = fmaxf(m1, hi);
        }
        const float inv = 1.0f / DEG;
        const float mean0 = s0*inv, var0 = fmaxf(q0*inv - mean0*mean0, 0.f);
        const float mean1 = s1*inv, var1 = fmaxf(q1*inv - mean1*mean1, 0.f);
        unsigned dmean = f2bf(mean0), dmax = f2bf(m0), dstd = f2bf(sqrtf(var0+1e-5f));
        if (hasHi) {
            dmean |= f2bf(mean1) << 16;
            dmax  |= f2bf(m1)    << 16;
            dstd  |= f2bf(sqrtf(var1+1e-5f)) << 16;
        }
        aggT[nl*ODW + f]         = dmean;
        aggT[nl*ODW + SEC + f]   = dmax;
        aggT[nl*ODW + 2*SEC + f] = dstd;
    } else if (NF == 9 && f == 5) {
        aggT[nl*ODW + 15] = 0u;                          // pad dword
    }
    __syncthreads();

    // park agg in the two mm-chunk slabs of d_out (nt: keep table L2-resident)
    constexpr int HALF = (GNPB/2) * ODW;                 // 384 or 256
    for (int i = t; i < GNPB * ODW; i += BLK) {
        const int s = i / HALF, j = i - s * HALF;
        __builtin_nontemporal_store(aggT[i],
            zdw + (size_t)(2*g0 + s) * 2048 + OOFF + j);
    }
}

__global__ __launch_bounds__(BLK) void mm(
    const float* __restrict__ snorm, const float* __restrict__ W,
    const float* __restrict__ bias, float* __restrict__ z,
    float* __restrict__ bnbuf)
{
    __shared__ ushort sA[MNPB * 48];
    __shared__ ushort sB[MNPB * 32];
    __shared__ ushort tile[MNPB * KPAD];

    const int t = threadIdx.x;
    const int lane = t & 63, wv = t >> 6;

    for (int i = t; i < MNPB * KPAD; i += BLK) tile[i] = 0;   // k>=75 stays 0

    const int cb0 = (wv*2+0)*16 + (lane & 15);
    const int cb1 = (wv*2+1)*16 + (lane & 15);
    short8 bfrag[2][3];
    #pragma unroll
    for (int ct = 0; ct < 2; ++ct) {
        const int cb = ct ? cb1 : cb0;
        #pragma unroll
        for (int kt = 0; kt < 3; ++kt) {
            short8 fr;
            #pragma unroll
            for (int j = 0; j < 8; ++j) {
                const int k = kt*32 + (lane>>4)*8 + j;
                const float w = (k < AGG_DIM) ? W[k * OUT_DIM + cb] : 0.0f;
                fr[j] = (short)f2bf(w);
            }
            bfrag[ct][kt] = fr;
        }
    }
    const float bb0 = bias[cb0], bb1 = bias[cb1];

    float bns0=0.f,bnq0=0.f,bns1=0.f,bnq1=0.f;
    const unsigned* zdw = (const unsigned*)z;

    for (int c = 0; c < 2; ++c) {
        const int chunk = blockIdx.x * 2 + c;
        const int n0 = chunk * MNPB;
        const unsigned* slab = zdw + (size_t)chunk * 2048;
        for (int i = t; i < 384; i += BLK) ((unsigned*)sA)[i] = slab[i];
        ((unsigned*)sB)[t] = slab[384 + t];
        __syncthreads();
        // assemble K=75 tile: W row order = mean(25)|max(25)|std(25)
        {
            const int n = t & 15;
            const ushort* rA = sA + n*48;
            const ushort* rB = sB + n*32;
            for (int k = t >> 4; k < AGG_DIM; k += 16) {
                ushort v;
                if      (k < 16) v = rA[k];          // mean A
                else if (k < 25) v = rB[k-16];       // mean B
                else if (k < 41) v = rA[k-9];        // max A  (16 + k-25)
                else if (k < 50) v = rB[k-31];       // max B  (10 + k-41)
                else if (k < 66) v = rA[k-18];       // std A  (32 + k-50)
                else             v = rB[k-46];       // std B  (20 + k-66)
                tile[n*KPAD + k] = v;
            }
        }
        __syncthreads();
        // MFMA + epilogue (overwrites this chunk's slab with z — same block, barrier-ordered)
        const int arow = lane & 15, ak0 = (lane>>4)*8;
        f32x4 acc0 = {0.f,0.f,0.f,0.f}, acc1 = {0.f,0.f,0.f,0.f};
        #pragma unroll
        for (int kt = 0; kt < 3; ++kt) {
            const short8 af = *(const short8*)(tile + arow*KPAD + kt*32 + ak0);
            acc0 = __builtin_amdgcn_mfma_f32_16x16x32_bf16(af, bfrag[0][kt], acc0, 0,0,0);
            acc1 = __builtin_amdgcn_mfma_f32_16x16x32_bf16(af, bfrag[1][kt], acc1, 0,0,0);
        }
        const int r0 = (lane>>4)*4;
        #pragma unroll
        for (int r = 0; r < 4; ++r) {
            const int node = n0 + r0 + r;
            const float sn = snorm[node];
            const float v0 = (acc0[r] + bb0) * sn;
            const float v1 = (acc1[r] + bb1) * sn;
            z[node*OUT_DIM + cb0] = v0;
            z[node*OUT_DIM + cb1] = v1;
            bns0 += v0; bnq0 = fmaf(v0,v0,bnq0);
            bns1 += v1; bnq1 = fmaf(v1,v1,bnq1);
        }
        __syncthreads();   // tile/sA reuse next iter; also orders z-writes vs slab reads
    }

    bns0 += __shfl_xor(bns0,16); bnq0 += __shfl_xor(bnq0,16);
    bns0 += __shfl_xor(bns0,32); bnq0 += __shfl_xor(bnq0,32);
    bns1 += __shfl_xor(bns1,16); bnq1 += __shfl_xor(bnq1,16);
    bns1 += __shfl_xor(bns1,32); bnq1 += __shfl_xor(bnq1,32);
    if ((lane >> 4) == 0) {
        atomicAdd(&bnbuf[cb0], bns0);
        atomicAdd(&bnbuf[OUT_DIM + cb0], bnq0);
        atomicAdd(&bnbuf[cb1], bns1);
        atomicAdd(&bnbuf[OUT_DIM + cb1], bnq1);
    }
}

__global__ __launch_bounds__(BLK) void bn_apply(
    const float* __restrict__ bnbuf, const float* __restrict__ gamma,
    const float* __restrict__ beta, float* __restrict__ z)
{
    __shared__ float sc_s[OUT_DIM], sh_s[OUT_DIM];
    const int t = threadIdx.x;
    if (t < OUT_DIM) {
        const float mu = bnbuf[t] * (1.0f / NN);
        const float v  = fmaxf(bnbuf[OUT_DIM + t] * (1.0f / NN) - mu * mu, 0.0f);
        const float sc = gamma[t] * rsqrtf(v + 1e-5f);
        sc_s[t] = sc;
        sh_s[t] = beta[t] - mu * sc;
    }
    __syncthreads();
    const int c4 = (t & 31) * 4;
    const float s0 = sc_s[c4], s1 = sc_s[c4+1], s2 = sc_s[c4+2], s3 = sc_s[c4+3];
    const float h0 = sh_s[c4], h1 = sh_s[c4+1], h2 = sh_s[c4+2], h3 = sh_s[c4+3];

    float4* z4 = (float4*)z;
    const int total4 = NN * (OUT_DIM / 4);
    for (int i = blockIdx.x * BLK + t; i < total4; i += gridDim.x * BLK) {
        float4 v = z4[i];
        v.x = fmaxf(fmaf(v.x, s0, h0), 0.f);
        v.y = fmaxf(fmaf(v.y, s1, h1), 0.f);
        v.z = fmaxf(fmaf(v.z, s2, h2), 0.f);
        v.w = fmaxf(fmaf(v.w, s3, h3), 0.f);
        z4[i] = v;
    }
}

extern "C" void kernel_launch(void* const* d_in, const int* in_sizes, int n_in,
                              void* d_out, int out_size, void* d_ws, size_t ws_size,
                              hipStream_t stream) {
    const float* h     = (const float*)d_in[0];
    const float* snorm = (const float*)d_in[1];
    const int*   esrc  = (const int*)d_in[2];
    // d_in[3] = edge_dst: repeat(arange(N), DEG) -> mailbox i = edges [32i, 32i+32)
    const float* W     = (const float*)d_in[4];
    const float* b     = (const float*)d_in[5];
    const float* gamma = (const float*)d_in[6];
    const float* beta  = (const float*)d_in[7];
    float*  z     = (float*)d_out;
    float*  bnbuf = (float*)d_ws;
    ushort* tabA  = (ushort*)((char*)d_ws + 1024);                       // 3.2 MB
    ushort* tabB  = (ushort*)((char*)d_ws + 1024 + (size_t)NN * 32);     // 3.2 MB

    prep<<<PREP_GRID, BLK, 0, stream>>>(h, tabA, tabB, bnbuf);
    gather_pass<16, 24, 0  ><<<GGRID, BLK, 0, stream>>>(tabA, esrc, (unsigned*)d_out);
    gather_pass< 9, 16, 384><<<GGRID, BLK, 0, stream>>>(tabB, esrc, (unsigned*)d_out);
    mm<<<MGRID, BLK, 0, stream>>>(snorm, W, b, z, bnbuf);
    bn_apply<<<2048, BLK, 0, stream>>>(bnbuf, gamma, beta, z);
}

// Round 6
// 175.464 us; speedup vs baseline: 1.3707x; 1.3707x over previous
//
#include <hip/hip_runtime.h>
#include <hip/hip_bf16.h>

#define NN 100000
#define DEG 32
#define IN_DIM 25
#define AGG_DIM 75
#define KPAD 104               // agg row stride (ushorts): 208 B = 13*16 -> b128-aligned
#define OUT_DIM 128
#define NPB 16                 // nodes per chunk == MFMA M-tile (fully used)
#define EPC (NPB * DEG)        // 512 edges per chunk
#define NCHUNK (NN / NPB)      // 6250
#define BLK 256
#define GRID 1024              // 4 blocks/CU at 38KB LDS; ~6 chunks per block
#define RGRID 64
#define PREP_GRID 391          // ceil(100000/256)

typedef __attribute__((ext_vector_type(8))) short short8;   // bf16 MFMA A/B frag
typedef __attribute__((ext_vector_type(4))) float f32x4;    // MFMA C/D frag

static __device__ __forceinline__ unsigned f2bf(float x) {
    __hip_bfloat16 h = __float2bfloat16(x);
    return (unsigned)*reinterpret_cast<unsigned short*>(&h);
}
static __device__ __forceinline__ float bflo(unsigned v) { return __uint_as_float(v << 16); }
static __device__ __forceinline__ float bfhi(unsigned v) { return __uint_as_float(v & 0xffff0000u); }

static __device__ __forceinline__ void gload16(const void* g, void* l) {
    __builtin_amdgcn_global_load_lds(
        (const __attribute__((address_space(1))) unsigned*)g,
        (__attribute__((address_space(3))) unsigned*)l, 16, 0, 0);
}

// ws layout: [0,1024) bnbuf (256 floats);
//            [1024, 1024+1MB) partials [GRID][256] floats (per-block BN sums);
//            [1049600, +6.4MB) h_bf16 padded [NN][32] ushorts (64B rows, 64B-aligned)
#define PARTIALS_OFF 1024
#define TABLE_OFF (1024 + GRID * 256 * 4)   // 1049600, 64B-aligned

__global__ __launch_bounds__(BLK) void prep(const float* __restrict__ h,
                                            ushort* __restrict__ hbp,
                                            float* __restrict__ bnbuf) {
    const int t = threadIdx.x;
    const int gid = blockIdx.x * BLK + t;
    if (gid < 2 * OUT_DIM) bnbuf[gid] = 0.0f;
    for (int n = gid; n < NN; n += PREP_GRID * BLK) {
        const float* row = h + n * IN_DIM;
        unsigned u[16];
        #pragma unroll
        for (int k = 0; k < 12; ++k) u[k] = f2bf(row[2 * k]) | (f2bf(row[2 * k + 1]) << 16);
        u[12] = f2bf(row[24]);
        u[13] = 0u; u[14] = 0u; u[15] = 0u;
        uint4* dst = (uint4*)(hbp + (size_t)n * 32);
        dst[0] = make_uint4(u[0], u[1], u[2], u[3]);
        dst[1] = make_uint4(u[4], u[5], u[6], u[7]);
        dst[2] = make_uint4(u[8], u[9], u[10], u[11]);
        dst[3] = make_uint4(u[12], u[13], u[14], u[15]);
    }
}

__global__ __launch_bounds__(BLK) void pna_main(
    const ushort* __restrict__ hb, const float* __restrict__ snorm,
    const int* __restrict__ esrc, const float* __restrict__ W,
    const float* __restrict__ b, float* __restrict__ z,
    float* __restrict__ partials)
{
    __shared__ __align__(1024) ushort E_s[EPC][32];   // 32 KB gathered edge rows (64B each)
    __shared__ int    ids_s[EPC];                     // 2 KB edge ids
    __shared__ ushort agg[NPB][KPAD];                 // 3.25 KB bf16 A-tile

    const int t = threadIdx.x;
    const int lane = t & 63;
    const int wv = t >> 6;

    // zero agg once (K-pad cols 75..103 stay zero forever)
    for (int i = t; i < NPB * KPAD; i += BLK) ((ushort*)agg)[i] = 0;

    // ---- W fragments (B operand), loaded once ----
    const int cb0 = (wv * 2 + 0) * 16 + (lane & 15);
    const int cb1 = (wv * 2 + 1) * 16 + (lane & 15);
    short8 bfrag[2][3];
    #pragma unroll
    for (int ct = 0; ct < 2; ++ct) {
        const int cb = ct ? cb1 : cb0;
        #pragma unroll
        for (int kt = 0; kt < 3; ++kt) {
            short8 fr;
            #pragma unroll
            for (int j = 0; j < 8; ++j) {
                const int k = kt * 32 + ((lane >> 4) * 8) + j;
                const float w = (k < AGG_DIM) ? W[k * OUT_DIM + cb] : 0.0f;
                fr[j] = (short)f2bf(w);
            }
            bfrag[ct][kt] = fr;
        }
    }
    const float bb0 = b[cb0], bb1 = b[cb1];

    // A1 constants: 4 lanes per row, 16B part each
    const int lsub = lane >> 2;          // row-within-group 0..15
    const int prt  = lane & 3;           // 16B part 0..3
    // A2 constants: 16 threads per node, dword-column f2 (covers features 2f2, 2f2+1)
    const int nl2 = t >> 4;              // node 0..15
    const int f2  = t & 15;              // active if < 13
    const bool a2act = (f2 < 13);
    const int dcol = f2 ^ ((nl2 & 3) << 2);   // XOR de-swizzle of stored dword index

    float bns0 = 0.f, bnq0 = 0.f, bns1 = 0.f, bnq1 = 0.f;

    for (int chunk = blockIdx.x; chunk < NCHUNK; chunk += GRID) {
        const int n0 = chunk * NPB;

        // ---- A0: stage 512 edge ids (coalesced 2 KB) ----
        ((int2*)ids_s)[t] = ((const int2*)(esrc + n0 * DEG))[t];
        __syncthreads();

        // ---- A1: row gather via global_load_lds (8 wave-instrs, 1 KB each) ----
        #pragma unroll
        for (int i = 0; i < 8; ++i) {
            const int g = wv * 8 + i;            // wave-uniform instr index 0..31
            const int r = g * 16 + lsub;         // edge row 0..511
            const int src = ids_s[r];
            const int psrc = prt ^ ((r >> 5) & 3);   // source-side XOR swizzle (dest linear)
            gload16((const char*)hb + ((size_t)src << 6) + (psrc << 4),
                    (char*)E_s + (g << 10));
        }
        __syncthreads();   // drains vmcnt: E_s ready

        // ---- A2: mean/max/std from LDS ----
        if (a2act) {
            const unsigned* Ew = (const unsigned*)E_s;
            const unsigned base = (unsigned)(nl2 * 512 + dcol);   // node row block (32 rows x 16 dw)
            float s0 = 0.f, q0 = 0.f, m0 = -3.4e38f;
            float s1 = 0.f, q1 = 0.f, m1 = -3.4e38f;
            #pragma unroll
            for (int e = 0; e < 32; ++e) {
                const int ee = (e + nl2) & 31;   // per-node rotation: bank spread + commutative
                const unsigned v = Ew[base + ee * 16];
                const float lo = bflo(v), hi = bfhi(v);
                s0 += lo; q0 = fmaf(lo, lo, q0); m0 = fmaxf(m0, lo);
                s1 += hi; q1 = fmaf(hi, hi, q1); m1 = fmaxf(m1, hi);
            }
            const float inv = 1.0f / DEG;
            const float mean0 = s0 * inv, var0 = fmaxf(q0 * inv - mean0 * mean0, 0.f);
            const float mean1 = s1 * inv, var1 = fmaxf(q1 * inv - mean1 * mean1, 0.f);
            const int ff = f2 * 2;
            agg[nl2][ff]              = (ushort)f2bf(mean0);
            agg[nl2][IN_DIM + ff]     = (ushort)f2bf(m0);
            agg[nl2][2 * IN_DIM + ff] = (ushort)f2bf(sqrtf(var0 + 1e-5f));
            if (ff + 1 < IN_DIM) {
                agg[nl2][ff + 1]              = (ushort)f2bf(mean1);
                agg[nl2][IN_DIM + ff + 1]     = (ushort)f2bf(m1);
                agg[nl2][2 * IN_DIM + ff + 1] = (ushort)f2bf(sqrtf(var1 + 1e-5f));
            }
        }
        __syncthreads();   // agg ready

        // ---- B: MFMA z = agg @ W, + b, * snorm; BN partials ----
        const int arow = lane & 15;
        const int ak0  = (lane >> 4) * 8;
        f32x4 acc0 = {0.f, 0.f, 0.f, 0.f}, acc1 = {0.f, 0.f, 0.f, 0.f};
        #pragma unroll
        for (int kt = 0; kt < 3; ++kt) {
            const short8 af = *reinterpret_cast<const short8*>(&agg[arow][kt * 32 + ak0]);
            acc0 = __builtin_amdgcn_mfma_f32_16x16x32_bf16(af, bfrag[0][kt], acc0, 0, 0, 0);
            acc1 = __builtin_amdgcn_mfma_f32_16x16x32_bf16(af, bfrag[1][kt], acc1, 0, 0, 0);
        }
        const int r0 = (lane >> 4) * 4;
        #pragma unroll
        for (int r = 0; r < 4; ++r) {
            const int node = n0 + r0 + r;
            const float sn = snorm[node];
            const float v0 = (acc0[r] + bb0) * sn;
            const float v1 = (acc1[r] + bb1) * sn;
            z[node * OUT_DIM + cb0] = v0;
            z[node * OUT_DIM + cb1] = v1;
            bns0 += v0; bnq0 = fmaf(v0, v0, bnq0);
            bns1 += v1; bnq1 = fmaf(v1, v1, bnq1);
        }
    }

    // ---- BN partials: wave reduce, then PRIVATE per-block slot (no atomics) ----
    bns0 += __shfl_xor(bns0, 16); bnq0 += __shfl_xor(bnq0, 16);
    bns0 += __shfl_xor(bns0, 32); bnq0 += __shfl_xor(bnq0, 32);
    bns1 += __shfl_xor(bns1, 16); bnq1 += __shfl_xor(bnq1, 16);
    bns1 += __shfl_xor(bns1, 32); bnq1 += __shfl_xor(bnq1, 32);
    if ((lane >> 4) == 0) {
        float* pp = partials + (size_t)blockIdx.x * 256;
        __builtin_nontemporal_store(bns0, pp + cb0);
        __builtin_nontemporal_store(bnq0, pp + OUT_DIM + cb0);
        __builtin_nontemporal_store(bns1, pp + cb1);
        __builtin_nontemporal_store(bnq1, pp + OUT_DIM + cb1);
    }
}

__global__ __launch_bounds__(BLK) void bn_reduce(const float* __restrict__ partials,
                                                 float* __restrict__ bnbuf) {
    const int t = threadIdx.x;
    float acc = 0.0f;
    for (int r = blockIdx.x; r < GRID; r += RGRID)
        acc += partials[(size_t)r * 256 + t];     // coalesced 1KB rows
    atomicAdd(&bnbuf[t], acc);                    // 64-deep chain only
}

__global__ __launch_bounds__(BLK) void bn_apply(
    const float* __restrict__ bnbuf, const float* __restrict__ gamma,
    const float* __restrict__ beta, float* __restrict__ z)
{
    __shared__ float sc_s[OUT_DIM], sh_s[OUT_DIM];
    const int t = threadIdx.x;
    if (t < OUT_DIM) {
        const float mu = bnbuf[t] * (1.0f / NN);
        const float v  = fmaxf(bnbuf[OUT_DIM + t] * (1.0f / NN) - mu * mu, 0.0f);
        const float sc = gamma[t] * rsqrtf(v + 1e-5f);
        sc_s[t] = sc;
        sh_s[t] = beta[t] - mu * sc;
    }
    __syncthreads();
    const int c4 = (t & 31) * 4;
    const float s0 = sc_s[c4], s1 = sc_s[c4+1], s2 = sc_s[c4+2], s3 = sc_s[c4+3];
    const float h0 = sh_s[c4], h1 = sh_s[c4+1], h2 = sh_s[c4+2], h3 = sh_s[c4+3];

    float4* z4 = (float4*)z;
    const int total4 = NN * (OUT_DIM / 4);
    for (int i = blockIdx.x * BLK + t; i < total4; i += gridDim.x * BLK) {
        float4 v = z4[i];
        v.x = fmaxf(fmaf(v.x, s0, h0), 0.f);
        v.y = fmaxf(fmaf(v.y, s1, h1), 0.f);
        v.z = fmaxf(fmaf(v.z, s2, h2), 0.f);
        v.w = fmaxf(fmaf(v.w, s3, h3), 0.f);
        z4[i] = v;
    }
}

extern "C" void kernel_launch(void* const* d_in, const int* in_sizes, int n_in,
                              void* d_out, int out_size, void* d_ws, size_t ws_size,
                              hipStream_t stream) {
    const float* h     = (const float*)d_in[0];
    const float* snorm = (const float*)d_in[1];
    const int*   esrc  = (const int*)d_in[2];
    // d_in[3] = edge_dst: repeat(arange(N), DEG) -> mailbox i = edges [32i, 32i+32)
    const float* W     = (const float*)d_in[4];
    const float* b     = (const float*)d_in[5];
    const float* gamma = (const float*)d_in[6];
    const float* beta  = (const float*)d_in[7];
    float*  z        = (float*)d_out;
    float*  bnbuf    = (float*)d_ws;
    float*  partials = (float*)((char*)d_ws + PARTIALS_OFF);   // 1 MB
    ushort* hbp      = (ushort*)((char*)d_ws + TABLE_OFF);     // [NN][32] bf16, 6.4 MB

    prep<<<PREP_GRID, BLK, 0, stream>>>(h, hbp, bnbuf);
    pna_main<<<GRID, BLK, 0, stream>>>(hbp, snorm, esrc, W, b, z, partials);
    bn_reduce<<<RGRID, BLK, 0, stream>>>(partials, bnbuf);
    bn_apply<<<2048, BLK, 0, stream>>>(bnbuf, gamma, beta, z);
}